// Round 3
// baseline (181.531 us; speedup 1.0000x reference)
//
#include <hip/hip_runtime.h>
#include <math.h>

#define NN 1024
#define KK 256
#define NH 4
#define FD 64
#define HF 256

typedef __attribute__((ext_vector_type(16))) float fx16;

// ---- workspace float offsets ----
#define OFF_GL   0
#define OFF_GR   (256*1024)
#define OFF_CL   (512*1024)
#define OFF_CR   (512*1024 + 4096)
#define OFF_DEN  (512*1024 + 8192)
#define OFF_P    (512*1024 + 12288)
#define OFF_ACCP (OFF_P + 4*1024*1024)

// ---------------- GEMM: g = A @ W, plus cl/cr epilogue ----------------
// grid (16 mb, 4 h, 2 mat), block 256 = 4 waves (one 16-f segment each).
// lane = m. A-tile staged in LDS [64m][256k]+pad; W rows streamed via VMEM
// (in-order, unroll-pipelined). Epilogue: LDS transpose -> coalesced stores;
// cl/cr = 0.6*sum_f w*g via atomicAdd of per-segment partials (linear, exact).
__global__ __launch_bounds__(256) void gatv2_gemm(
    const float* __restrict__ hmat, const float* __restrict__ nei,
    const float* __restrict__ w_l, const float* __restrict__ w_r,
    const float* __restrict__ aw, float* __restrict__ ws)
{
    __shared__ float sA[64*257];   // 65792 B; reused (64*65) for transpose
    const int t  = threadIdx.x;
    const int mb = blockIdx.x;
    const int hh = blockIdx.y;
    const int mat = blockIdx.z;
    const float* A = mat ? nei : hmat;
    const float* W = mat ? w_r : w_l;
    float* G  = ws + (mat ? OFF_GR : OFF_GL);
    float* CC = ws + (mat ? OFF_CR : OFF_CL);

    const int lane = t & 63;
    const int wv   = t >> 6;
    const int m    = mb*64 + lane;
    const int n0   = hh*64 + wv*16;

    // stage A tile [64][256] -> sA stride 257
    #pragma unroll
    for (int rep = 0; rep < 16; ++rep) {
        const int flat = rep*1024 + t*4;
        const int r = flat >> 8, c = flat & 255;
        *(float4*)&sA[r*257 + c] = *(const float4*)&A[(size_t)(mb*64 + r)*KK + c];
    }
    __syncthreads();

    float acc[16] = {};
    const float* wp = W + n0;
    #pragma unroll 4
    for (int k = 0; k < KK; ++k) {
        const float a = sA[lane*257 + k];
        const float4 w0 = *(const float4*)(wp + (size_t)k*HF);
        const float4 w1 = *(const float4*)(wp + (size_t)k*HF + 4);
        const float4 w2 = *(const float4*)(wp + (size_t)k*HF + 8);
        const float4 w3 = *(const float4*)(wp + (size_t)k*HF + 12);
        acc[0]  += a*w0.x; acc[1]  += a*w0.y; acc[2]  += a*w0.z; acc[3]  += a*w0.w;
        acc[4]  += a*w1.x; acc[5]  += a*w1.y; acc[6]  += a*w1.z; acc[7]  += a*w1.w;
        acc[8]  += a*w2.x; acc[9]  += a*w2.y; acc[10] += a*w2.z; acc[11] += a*w2.w;
        acc[12] += a*w3.x; acc[13] += a*w3.y; acc[14] += a*w3.z; acc[15] += a*w3.w;
    }

    // cl/cr partial: 0.6 * sum_{f in seg} w[f]*acc[f]
    {
        const float4* awp = (const float4*)(aw + wv*16);
        float wd = 0.f;
        #pragma unroll
        for (int c = 0; c < 4; ++c) {
            const float4 w4 = awp[c];
            wd += w4.x*acc[c*4] + w4.y*acc[c*4+1] + w4.z*acc[c*4+2] + w4.w*acc[c*4+3];
        }
        atomicAdd(&CC[hh*NN + m], 0.6f*wd);
    }

    // transpose via LDS -> coalesced G stores
    __syncthreads();
    #pragma unroll
    for (int c = 0; c < 4; ++c)
        *(float4*)&sA[lane*65 + wv*16 + c*4] =
            make_float4(acc[c*4], acc[c*4+1], acc[c*4+2], acc[c*4+3]);
    __syncthreads();
    #pragma unroll
    for (int rep = 0; rep < 4; ++rep) {
        const int flat = rep*1024 + t*4;
        const int ml = flat >> 6, f = flat & 63;
        const float4 v = *(const float4*)&sA[ml*65 + f];
        *(float4*)&G[(size_t)(mb*64 + ml)*HF + hh*64 + f] = v;
    }
}

// ---------------- Phase A: e -> p = mask*exp(e), den atomics ----------------
// thread = one i, lane-contiguous. g_l[j] row enters via SMEM (s_load_dwordx16
// x4 + cl dword, wait inside one asm block => no use-before-wait hazard).
// Inner loop: v_add(s,v) + v_fma(w, |t|, e) — zero LDS, 2 VMEM per j.
#define EBLK(RV, QB)                                              \
    { _Pragma("unroll") for (int q = 0; q < 4; ++q) {             \
        const float4 wq = w[(QB)+q]; const float4 gq = gri[(QB)+q]; \
        e0 += wq.x * fabsf(RV[q*4+0] + gq.x);                     \
        e1 += wq.y * fabsf(RV[q*4+1] + gq.y);                     \
        e2 += wq.z * fabsf(RV[q*4+2] + gq.z);                     \
        e3 += wq.w * fabsf(RV[q*4+3] + gq.w); } }

__global__ __launch_bounds__(256, 3) void gatv2_e(
    const float* __restrict__ wsro, const float* __restrict__ adj,
    const float* __restrict__ aw, float* __restrict__ P,
    float* __restrict__ den)
{
    const float* g_l = wsro + OFF_GL;
    const float* g_r = wsro + OFF_GR;
    const float* cl  = wsro + OFF_CL;
    const float* cr  = wsro + OFF_CR;
    const int t  = threadIdx.x;
    const int jc = blockIdx.x;   // 32 j-chunks of 32
    const int ib = blockIdx.y;   // 4
    const int hh = blockIdx.z;   // 4
    const int i  = ib*256 + t;

    float4 w[16], gri[16];
    {
        const float4* awp = (const float4*)aw;
        const float4* gp  = (const float4*)(g_r + (size_t)i*HF + hh*FD);
        #pragma unroll
        for (int q = 0; q < 16; ++q) { w[q] = awp[q]; gri[q] = gp[q]; }
    }
    const float cri = cr[hh*NN + i];

    float denl = 0.f;
    const int j0 = jc*32;
    for (int jj = 0; jj < 32; ++jj) {
        const int j = j0 + jj;
        const float mask = adj[(size_t)j*NN + i];
        fx16 r0, r1, r2, r3; float clv;
        const float* rowp = g_l + (size_t)j*HF + hh*FD;
        const float* clp  = cl + hh*NN + j;
        asm volatile(
            "s_load_dwordx16 %0, %5, 0x0\n\t"
            "s_load_dwordx16 %1, %5, 0x40\n\t"
            "s_load_dwordx16 %2, %5, 0x80\n\t"
            "s_load_dwordx16 %3, %5, 0xc0\n\t"
            "s_load_dword %4, %6, 0x0\n\t"
            "s_waitcnt lgkmcnt(0)"
            : "=s"(r0), "=s"(r1), "=s"(r2), "=s"(r3), "=s"(clv)
            : "s"(rowp), "s"(clp));
        float e0 = 0.f, e1 = 0.f, e2 = 0.f, e3 = 0.f;
        EBLK(r0, 0) EBLK(r1, 4) EBLK(r2, 8) EBLK(r3, 12)
        const float e  = cri + clv + 0.4f*((e0+e1)+(e2+e3));
        const float pw = (mask != 0.f) ? __expf(e) : 0.f;
        denl += pw;
        P[((size_t)hh*NN + j)*NN + i] = pw;
    }
    atomicAdd(&den[hh*NN + i], denl);
}

// ---------------- Phase B: accP[jc] = P-chunk @ g_r ----------------
// wave = (16-f segment, 64 lanes = i), thread covers i and i+64.
// g_r segment: 4 uniform b128 VMEM (in-order, unroll-pipelined); P coalesced.
// Epilogue: LDS transpose -> out-layout coalesced partial stores.
__global__ __launch_bounds__(256) void gatv2_pv(
    const float* __restrict__ wsro, float* __restrict__ accP, int JC2)
{
    __shared__ float sT[128*65];
    const float* g_r = wsro + OFF_GR;
    const float* P   = wsro + OFF_P;
    const int t  = threadIdx.x;
    const int jc = blockIdx.x;      // JC2
    const int ib = blockIdx.y;      // 8 (128 i's each)
    const int hh = blockIdx.z;      // 4
    const int wv = t >> 6, l = t & 63;
    const int i1 = ib*128 + l;
    const int f0 = hh*FD + wv*16;
    const int JPB = NN / JC2;

    float4 a1[4] = {}, a2[4] = {};
    const int j0 = jc*JPB;
    #pragma unroll 2
    for (int jj = 0; jj < JPB; ++jj) {
        const int j = j0 + jj;
        const float* rp = g_r + (size_t)j*HF + f0;
        const float4 r0 = ((const float4*)rp)[0];
        const float4 r1 = ((const float4*)rp)[1];
        const float4 r2 = ((const float4*)rp)[2];
        const float4 r3 = ((const float4*)rp)[3];
        const size_t pbase = ((size_t)hh*NN + j)*NN + i1;
        const float p1 = P[pbase];
        const float p2 = P[pbase + 64];
        a1[0].x += p1*r0.x; a1[0].y += p1*r0.y; a1[0].z += p1*r0.z; a1[0].w += p1*r0.w;
        a1[1].x += p1*r1.x; a1[1].y += p1*r1.y; a1[1].z += p1*r1.z; a1[1].w += p1*r1.w;
        a1[2].x += p1*r2.x; a1[2].y += p1*r2.y; a1[2].z += p1*r2.z; a1[2].w += p1*r2.w;
        a1[3].x += p1*r3.x; a1[3].y += p1*r3.y; a1[3].z += p1*r3.z; a1[3].w += p1*r3.w;
        a2[0].x += p2*r0.x; a2[0].y += p2*r0.y; a2[0].z += p2*r0.z; a2[0].w += p2*r0.w;
        a2[1].x += p2*r1.x; a2[1].y += p2*r1.y; a2[1].z += p2*r1.z; a2[1].w += p2*r1.w;
        a2[2].x += p2*r2.x; a2[2].y += p2*r2.y; a2[2].z += p2*r2.z; a2[2].w += p2*r2.w;
        a2[3].x += p2*r3.x; a2[3].y += p2*r3.y; a2[3].z += p2*r3.z; a2[3].w += p2*r3.w;
    }

    // transpose 128i x 64f tile via LDS, then coalesced stores in out-layout
    #pragma unroll
    for (int c = 0; c < 4; ++c) {
        *(float4*)&sT[(l     )*65 + wv*16 + c*4] = a1[c];
        *(float4*)&sT[(l + 64)*65 + wv*16 + c*4] = a2[c];
    }
    __syncthreads();
    #pragma unroll
    for (int rep = 0; rep < 8; ++rep) {
        const int flat = rep*1024 + t*4;
        const int il = flat >> 6, f = flat & 63;
        const float4 v = *(const float4*)&sT[il*65 + f];
        *(float4*)&accP[(size_t)jc*(NN*HF) + (size_t)(ib*128 + il)*HF + hh*64 + f] = v;
    }
}

// ---------------- Final: sum partials, /den, elu ----------------
__global__ __launch_bounds__(256) void gatv2_fin(
    const float* __restrict__ accP, const float* __restrict__ den,
    const int* __restrict__ use_elu, float* __restrict__ out, int JC2)
{
    const int idx = blockIdx.x*256 + threadIdx.x;   // i*256 + h*64 + f
    const int i = idx >> 8, hh = (idx >> 6) & 3;
    float s = 0.f;
    for (int c = 0; c < JC2; ++c) s += accP[(size_t)c*(NN*HF) + idx];
    float r = s / den[hh*NN + i];
    if (*use_elu != 0) r = (r > 0.f) ? r : expm1f(r);
    out[idx] = r;
}

extern "C" void kernel_launch(void* const* d_in, const int* in_sizes, int n_in,
                              void* d_out, int out_size, void* d_ws, size_t ws_size,
                              hipStream_t stream)
{
    const float* hmat = (const float*)d_in[0];
    const float* nei  = (const float*)d_in[1];
    const float* adj  = (const float*)d_in[2];
    const float* w_l  = (const float*)d_in[3];
    const float* w_r  = (const float*)d_in[4];
    const float* aw   = (const float*)d_in[5];
    const int*   uel  = (const int*)d_in[6];
    float* out = (float*)d_out;
    float* ws  = (float*)d_ws;

    int JC2 = 16;
    if (((size_t)OFF_ACCP + (size_t)16*NN*HF) * 4 > ws_size) JC2 = 8;

    // zero cl, cr, den (ws is poisoned 0xAA before every launch)
    hipMemsetAsync((void*)(ws + OFF_CL), 0, 3*4096*sizeof(float), stream);

    hipLaunchKernelGGL(gatv2_gemm, dim3(16,4,2), dim3(256), 0, stream,
                       hmat, nei, w_l, w_r, aw, ws);
    hipLaunchKernelGGL(gatv2_e, dim3(32,4,4), dim3(256), 0, stream,
                       ws, adj, aw, ws + OFF_P, ws + OFF_DEN);
    hipLaunchKernelGGL(gatv2_pv, dim3(JC2,8,4), dim3(256), 0, stream,
                       ws, ws + OFF_ACCP, JC2);
    hipLaunchKernelGGL(gatv2_fin, dim3((NN*HF)/256), dim3(256), 0, stream,
                       ws + OFF_ACCP, ws + OFF_DEN, uel, out, JC2);
}

// Round 4
// 157.752 us; speedup vs baseline: 1.1507x; 1.1507x over previous
//
#include <hip/hip_runtime.h>
#include <math.h>

#define NN 1024
#define KK 256
#define NH 4
#define FD 64
#define HF 256

typedef __attribute__((ext_vector_type(16))) float fx16;

// ---- workspace float offsets ----
#define OFF_GL   0
#define OFF_GR   (256*1024)
#define OFF_CL   (512*1024)
#define OFF_CR   (512*1024 + 4096)
#define OFF_DENP (512*1024 + 8192)          // 32 chunks x 4096
#define OFF_P    (768*1024)
#define OFF_ACCP (OFF_P + 4*1024*1024)

// ---------------- GEMM: G = A @ W, cl/cr fused, no atomics ----------------
// grid (64 mb, 4 head, 2 mat) = 512 blocks (2/CU). Block: 16 rows x 64 cols
// (one head's f-range). A tile (16x256) staged in LDS, read as b128 broadcast;
// W streamed via coalesced VMEM (lanes cover 64 cols). Thread = 1m x 4n.
// Per 4k: 1 ds_read_b128 + 4 vmem b128 + 16 FMA -> VMEM-issue bound ~4us.
__global__ __launch_bounds__(256) void gatv2_gemm(
    const float* __restrict__ hmat, const float* __restrict__ nei,
    const float* __restrict__ w_l, const float* __restrict__ w_r,
    const float* __restrict__ aw, float* __restrict__ ws)
{
    __shared__ float sA[16*260];   // 16 rows x 256 k, +4 pad
    const int t   = threadIdx.x;
    const int mb  = blockIdx.x;
    const int hd  = blockIdx.y;
    const int mat = blockIdx.z;
    const float* A = mat ? nei : hmat;
    const float* W = mat ? w_r : w_l;
    float* G  = ws + (mat ? OFF_GR : OFF_GL);
    float* CC = ws + (mat ? OFF_CR : OFF_CL);

    // stage A tile: 16 rows x 256 k (coalesced b128)
    #pragma unroll
    for (int rep = 0; rep < 4; ++rep) {
        const int flat = rep*256 + t;        // float4 index
        const int r = flat >> 6, c = (flat & 63) << 2;
        *(float4*)&sA[r*260 + c] = *(const float4*)&A[(size_t)(mb*16 + r)*KK + c];
    }
    __syncthreads();

    const int m  = t >> 4;          // 0..15
    const int nq = t & 15;          // 4-col group within head
    const int ng = hd*64 + (nq << 2);
    const float* Wp = W + ng;

    float4 acc = make_float4(0.f, 0.f, 0.f, 0.f);
    #pragma unroll 4
    for (int k0 = 0; k0 < KK; k0 += 4) {
        const float4 a4 = *(const float4*)&sA[m*260 + k0];
        const float4 w0 = *(const float4*)(Wp + (size_t)(k0+0)*HF);
        const float4 w1 = *(const float4*)(Wp + (size_t)(k0+1)*HF);
        const float4 w2 = *(const float4*)(Wp + (size_t)(k0+2)*HF);
        const float4 w3 = *(const float4*)(Wp + (size_t)(k0+3)*HF);
        acc.x += a4.x*w0.x; acc.y += a4.x*w0.y; acc.z += a4.x*w0.z; acc.w += a4.x*w0.w;
        acc.x += a4.y*w1.x; acc.y += a4.y*w1.y; acc.z += a4.y*w1.z; acc.w += a4.y*w1.w;
        acc.x += a4.z*w2.x; acc.y += a4.z*w2.y; acc.z += a4.z*w2.z; acc.w += a4.z*w2.w;
        acc.x += a4.w*w3.x; acc.y += a4.w*w3.y; acc.z += a4.w*w3.z; acc.w += a4.w*w3.w;
    }

    // store G row-chunk (coalesced 256B per 16-lane group)
    *(float4*)&G[(size_t)(mb*16 + m)*HF + ng] = acc;

    // cl/cr: 0.6 * sum_f w[f]*g[m,f] ; segment dot then xor-reduce over nq
    {
        const float4 w4 = ((const float4*)aw)[nq];
        float wd = w4.x*acc.x + w4.y*acc.y + w4.z*acc.z + w4.w*acc.w;
        wd += __shfl_xor(wd, 1);
        wd += __shfl_xor(wd, 2);
        wd += __shfl_xor(wd, 4);
        wd += __shfl_xor(wd, 8);
        if (nq == 0) CC[hd*NN + mb*16 + m] = 0.6f*wd;
    }
}

// ---------------- Phase A: e -> p = mask*exp(e), chunked den ----------------
#define EBLK(RV, QB)                                                \
    { _Pragma("unroll") for (int q = 0; q < 4; ++q) {               \
        const float4 wq = w[(QB)+q]; const float4 gq = gri[(QB)+q]; \
        e0 += wq.x * fabsf(RV[q*4+0] + gq.x);                       \
        e1 += wq.y * fabsf(RV[q*4+1] + gq.y);                       \
        e2 += wq.z * fabsf(RV[q*4+2] + gq.z);                       \
        e3 += wq.w * fabsf(RV[q*4+3] + gq.w); } }

__global__ __launch_bounds__(256, 3) void gatv2_e(
    const float* __restrict__ wsro, const float* __restrict__ adj,
    const float* __restrict__ aw, float* __restrict__ P,
    float* __restrict__ denP)
{
    const float* g_l = wsro + OFF_GL;
    const float* g_r = wsro + OFF_GR;
    const float* cl  = wsro + OFF_CL;
    const float* cr  = wsro + OFF_CR;
    const int t  = threadIdx.x;
    const int jc = blockIdx.x;   // 32 j-chunks of 32
    const int ib = blockIdx.y;   // 4
    const int hh = blockIdx.z;   // 4
    const int i  = ib*256 + t;

    float4 w[16], gri[16];
    {
        const float4* awp = (const float4*)aw;
        const float4* gp  = (const float4*)(g_r + (size_t)i*HF + hh*FD);
        #pragma unroll
        for (int q = 0; q < 16; ++q) { w[q] = awp[q]; gri[q] = gp[q]; }
    }
    const float cri = cr[hh*NN + i];

    float denl = 0.f;
    const int j0 = jc*32;
    for (int jj = 0; jj < 32; ++jj) {
        const int j = j0 + jj;
        const float mask = adj[(size_t)j*NN + i];
        fx16 r0, r1, r2, r3; float clv;
        const float* rowp = g_l + (size_t)j*HF + hh*FD;
        const float* clp  = cl + hh*NN + j;
        asm volatile(
            "s_load_dwordx16 %0, %5, 0x0\n\t"
            "s_load_dwordx16 %1, %5, 0x40\n\t"
            "s_load_dwordx16 %2, %5, 0x80\n\t"
            "s_load_dwordx16 %3, %5, 0xc0\n\t"
            "s_load_dword %4, %6, 0x0\n\t"
            "s_waitcnt lgkmcnt(0)"
            : "=s"(r0), "=s"(r1), "=s"(r2), "=s"(r3), "=s"(clv)
            : "s"(rowp), "s"(clp));
        float e0 = 0.f, e1 = 0.f, e2 = 0.f, e3 = 0.f;
        EBLK(r0, 0) EBLK(r1, 4) EBLK(r2, 8) EBLK(r3, 12)
        const float e  = cri + clv + 0.4f*((e0+e1)+(e2+e3));
        const float pw = (mask != 0.f) ? __expf(e) : 0.f;
        denl += pw;
        P[((size_t)hh*NN + j)*NN + i] = pw;
    }
    denP[(size_t)jc*(NN*NH) + hh*NN + i] = denl;   // plain store, no atomics
}

// ---------------- Phase B: accP[jc] = P-chunk @ g_r ----------------
__global__ __launch_bounds__(256) void gatv2_pv(
    const float* __restrict__ wsro, float* __restrict__ accP, int JC2)
{
    __shared__ float sT[128*65];
    const float* g_r = wsro + OFF_GR;
    const float* P   = wsro + OFF_P;
    const int t  = threadIdx.x;
    const int jc = blockIdx.x;      // JC2
    const int ib = blockIdx.y;      // 8 (128 i's each)
    const int hh = blockIdx.z;      // 4
    const int wv = t >> 6, l = t & 63;
    const int i1 = ib*128 + l;
    const int f0 = hh*FD + wv*16;
    const int JPB = NN / JC2;

    float4 a1[4] = {}, a2[4] = {};
    const int j0 = jc*JPB;
    #pragma unroll 2
    for (int jj = 0; jj < JPB; ++jj) {
        const int j = j0 + jj;
        const float* rp = g_r + (size_t)j*HF + f0;
        const float4 r0 = ((const float4*)rp)[0];
        const float4 r1 = ((const float4*)rp)[1];
        const float4 r2 = ((const float4*)rp)[2];
        const float4 r3 = ((const float4*)rp)[3];
        const size_t pbase = ((size_t)hh*NN + j)*NN + i1;
        const float p1 = P[pbase];
        const float p2 = P[pbase + 64];
        a1[0].x += p1*r0.x; a1[0].y += p1*r0.y; a1[0].z += p1*r0.z; a1[0].w += p1*r0.w;
        a1[1].x += p1*r1.x; a1[1].y += p1*r1.y; a1[1].z += p1*r1.z; a1[1].w += p1*r1.w;
        a1[2].x += p1*r2.x; a1[2].y += p1*r2.y; a1[2].z += p1*r2.z; a1[2].w += p1*r2.w;
        a1[3].x += p1*r3.x; a1[3].y += p1*r3.y; a1[3].z += p1*r3.z; a1[3].w += p1*r3.w;
        a2[0].x += p2*r0.x; a2[0].y += p2*r0.y; a2[0].z += p2*r0.z; a2[0].w += p2*r0.w;
        a2[1].x += p2*r1.x; a2[1].y += p2*r1.y; a2[1].z += p2*r1.z; a2[1].w += p2*r1.w;
        a2[2].x += p2*r2.x; a2[2].y += p2*r2.y; a2[2].z += p2*r2.z; a2[2].w += p2*r2.w;
        a2[3].x += p2*r3.x; a2[3].y += p2*r3.y; a2[3].z += p2*r3.z; a2[3].w += p2*r3.w;
    }

    #pragma unroll
    for (int c = 0; c < 4; ++c) {
        *(float4*)&sT[(l     )*65 + wv*16 + c*4] = a1[c];
        *(float4*)&sT[(l + 64)*65 + wv*16 + c*4] = a2[c];
    }
    __syncthreads();
    #pragma unroll
    for (int rep = 0; rep < 8; ++rep) {
        const int flat = rep*1024 + t*4;
        const int il = flat >> 6, f = flat & 63;
        const float4 v = *(const float4*)&sT[il*65 + f];
        *(float4*)&accP[(size_t)jc*(NN*HF) + (size_t)(ib*128 + il)*HF + hh*64 + f] = v;
    }
}

// ---------------- Final: sum partials, /den, elu ----------------
__global__ __launch_bounds__(256) void gatv2_fin(
    const float* __restrict__ accP, const float* __restrict__ denP,
    const int* __restrict__ use_elu, float* __restrict__ out, int JC2)
{
    const int idx4 = blockIdx.x*256 + threadIdx.x;  // float4 index over out
    const int i  = idx4 >> 6;
    const int hh = (idx4 >> 4) & 3;
    float4 s = make_float4(0.f,0.f,0.f,0.f);
    for (int c = 0; c < JC2; ++c) {
        const float4 v = *(const float4*)&accP[(size_t)c*(NN*HF) + (size_t)idx4*4];
        s.x += v.x; s.y += v.y; s.z += v.z; s.w += v.w;
    }
    float d = 0.f;
    for (int c = 0; c < 32; ++c) d += denP[(size_t)c*(NN*NH) + hh*NN + i];
    const float rd = 1.f / d;
    float4 r = make_float4(s.x*rd, s.y*rd, s.z*rd, s.w*rd);
    if (*use_elu != 0) {
        r.x = (r.x > 0.f) ? r.x : expm1f(r.x);
        r.y = (r.y > 0.f) ? r.y : expm1f(r.y);
        r.z = (r.z > 0.f) ? r.z : expm1f(r.z);
        r.w = (r.w > 0.f) ? r.w : expm1f(r.w);
    }
    ((float4*)out)[idx4] = r;
}

extern "C" void kernel_launch(void* const* d_in, const int* in_sizes, int n_in,
                              void* d_out, int out_size, void* d_ws, size_t ws_size,
                              hipStream_t stream)
{
    const float* hmat = (const float*)d_in[0];
    const float* nei  = (const float*)d_in[1];
    const float* adj  = (const float*)d_in[2];
    const float* w_l  = (const float*)d_in[3];
    const float* w_r  = (const float*)d_in[4];
    const float* aw   = (const float*)d_in[5];
    const int*   uel  = (const int*)d_in[6];
    float* out = (float*)d_out;
    float* ws  = (float*)d_ws;

    int JC2 = 16;
    if (((size_t)OFF_ACCP + (size_t)16*NN*HF) * 4 > ws_size) JC2 = 8;

    hipLaunchKernelGGL(gatv2_gemm, dim3(64,4,2), dim3(256), 0, stream,
                       hmat, nei, w_l, w_r, aw, ws);
    hipLaunchKernelGGL(gatv2_e, dim3(32,4,4), dim3(256), 0, stream,
                       ws, adj, aw, ws + OFF_P, ws + OFF_DENP);
    hipLaunchKernelGGL(gatv2_pv, dim3(JC2,8,4), dim3(256), 0, stream,
                       ws, ws + OFF_ACCP, JC2);
    hipLaunchKernelGGL(gatv2_fin, dim3((NN*HF)/1024), dim3(256), 0, stream,
                       ws + OFF_ACCP, ws + OFF_DENP, uel, out, JC2);
}

// Round 5
// 145.831 us; speedup vs baseline: 1.2448x; 1.0817x over previous
//
#include <hip/hip_runtime.h>
#include <math.h>

#define NN 1024
#define KK 256
#define NH 4
#define FD 64
#define HF 256

typedef __attribute__((ext_vector_type(16))) float fx16;

// ---- workspace float offsets ----
#define OFF_GL   0
#define OFF_GR   (256*1024)
#define OFF_CL   (512*1024)
#define OFF_CR   (512*1024 + 4096)
#define OFF_DENP (512*1024 + 8192)          // 32 chunks x 4096
#define OFF_P    (768*1024)                 // 4M floats [h][j][i]
#define OFF_ACCP (OFF_P + 4*1024*1024)      // 16 chunks x 256K

// ---------------- GEMM: G = A @ W, cl/cr fused, no atomics ----------------
// (unchanged from R4 — stayed out of top-5)
__global__ __launch_bounds__(256) void gatv2_gemm(
    const float* __restrict__ hmat, const float* __restrict__ nei,
    const float* __restrict__ w_l, const float* __restrict__ w_r,
    const float* __restrict__ aw, float* __restrict__ ws)
{
    __shared__ float sA[16*260];
    const int t   = threadIdx.x;
    const int mb  = blockIdx.x;
    const int hd  = blockIdx.y;
    const int mat = blockIdx.z;
    const float* A = mat ? nei : hmat;
    const float* W = mat ? w_r : w_l;
    float* G  = ws + (mat ? OFF_GR : OFF_GL);
    float* CC = ws + (mat ? OFF_CR : OFF_CL);

    #pragma unroll
    for (int rep = 0; rep < 4; ++rep) {
        const int flat = rep*256 + t;
        const int r = flat >> 6, c = (flat & 63) << 2;
        *(float4*)&sA[r*260 + c] = *(const float4*)&A[(size_t)(mb*16 + r)*KK + c];
    }
    __syncthreads();

    const int m  = t >> 4;
    const int nq = t & 15;
    const int ng = hd*64 + (nq << 2);
    const float* Wp = W + ng;

    float4 acc = make_float4(0.f, 0.f, 0.f, 0.f);
    #pragma unroll 4
    for (int k0 = 0; k0 < KK; k0 += 4) {
        const float4 a4 = *(const float4*)&sA[m*260 + k0];
        const float4 w0 = *(const float4*)(Wp + (size_t)(k0+0)*HF);
        const float4 w1 = *(const float4*)(Wp + (size_t)(k0+1)*HF);
        const float4 w2 = *(const float4*)(Wp + (size_t)(k0+2)*HF);
        const float4 w3 = *(const float4*)(Wp + (size_t)(k0+3)*HF);
        acc.x += a4.x*w0.x; acc.y += a4.x*w0.y; acc.z += a4.x*w0.z; acc.w += a4.x*w0.w;
        acc.x += a4.y*w1.x; acc.y += a4.y*w1.y; acc.z += a4.y*w1.z; acc.w += a4.y*w1.w;
        acc.x += a4.z*w2.x; acc.y += a4.z*w2.y; acc.z += a4.z*w2.z; acc.w += a4.z*w2.w;
        acc.x += a4.w*w3.x; acc.y += a4.w*w3.y; acc.z += a4.w*w3.z; acc.w += a4.w*w3.w;
    }

    *(float4*)&G[(size_t)(mb*16 + m)*HF + ng] = acc;

    {
        const float4 w4 = ((const float4*)aw)[nq];
        float wd = w4.x*acc.x + w4.y*acc.y + w4.z*acc.z + w4.w*acc.w;
        wd += __shfl_xor(wd, 1);
        wd += __shfl_xor(wd, 2);
        wd += __shfl_xor(wd, 4);
        wd += __shfl_xor(wd, 8);
        if (nq == 0) CC[hd*NN + mb*16 + m] = 0.6f*wd;
    }
}

// ---------------- Phase A: e -> p = mask*exp(e), chunked den ----------------
// w staged via LDS -> per-lane ds_read -> VGPRs (NOT SGPRs: keeps scalar file
// free for the streamed g_l row; R4's 48-VGPR/AGPR-spill disaster was SGPR
// overflow cascade). Row enters via s_load_dwordx16 x4 (SMEM pipe).
#define EBLK(RV, QB)                                                \
    { _Pragma("unroll") for (int q = 0; q < 4; ++q) {               \
        const float4 wq = w[(QB)+q]; const float4 gq = gri[(QB)+q]; \
        e0 += wq.x * fabsf(RV[q*4+0] + gq.x);                       \
        e1 += wq.y * fabsf(RV[q*4+1] + gq.y);                       \
        e2 += wq.z * fabsf(RV[q*4+2] + gq.z);                       \
        e3 += wq.w * fabsf(RV[q*4+3] + gq.w); } }

__global__ __launch_bounds__(256, 3) void gatv2_e(
    const float* __restrict__ wsro, const float* __restrict__ adj,
    const float* __restrict__ aw, float* __restrict__ P,
    float* __restrict__ denP)
{
    __shared__ float s_w[64];
    const float* g_l = wsro + OFF_GL;
    const float* g_r = wsro + OFF_GR;
    const float* cl  = wsro + OFF_CL;
    const float* cr  = wsro + OFF_CR;
    const int t  = threadIdx.x;
    const int jc = blockIdx.x;   // 32 j-chunks of 32
    const int ib = blockIdx.y;   // 4
    const int hh = blockIdx.z;   // 4
    const int i  = ib*256 + t;

    if (t < 16) ((float4*)s_w)[t] = ((const float4*)aw)[t];
    __syncthreads();

    float4 w[16], gri[16];
    {
        const float4* gp = (const float4*)(g_r + (size_t)i*HF + hh*FD);
        #pragma unroll
        for (int q = 0; q < 16; ++q) {
            w[q]   = ((const float4*)s_w)[q];   // ds_read -> VGPR, per-lane
            gri[q] = gp[q];
        }
    }
    const float cri = cr[hh*NN + i];

    float denl = 0.f;
    const int j0 = jc*32;
    for (int jj = 0; jj < 32; ++jj) {
        const int j = j0 + jj;
        const float mask = adj[(size_t)j*NN + i];
        fx16 r0, r1, r2, r3; float clv;
        const float* rowp = g_l + (size_t)j*HF + hh*FD;
        const float* clp  = cl + hh*NN + j;
        asm volatile(
            "s_load_dwordx16 %0, %5, 0x0\n\t"
            "s_load_dwordx16 %1, %5, 0x40\n\t"
            "s_load_dwordx16 %2, %5, 0x80\n\t"
            "s_load_dwordx16 %3, %5, 0xc0\n\t"
            "s_load_dword %4, %6, 0x0\n\t"
            "s_waitcnt lgkmcnt(0)"
            : "=s"(r0), "=s"(r1), "=s"(r2), "=s"(r3), "=s"(clv)
            : "s"(rowp), "s"(clp));
        float e0 = 0.f, e1 = 0.f, e2 = 0.f, e3 = 0.f;
        EBLK(r0, 0) EBLK(r1, 4) EBLK(r2, 8) EBLK(r3, 12)
        const float e  = cri + clv + 0.4f*((e0+e1)+(e2+e3));
        const float pw = (mask != 0.f) ? __expf(e) : 0.f;
        denl += pw;
        P[((size_t)hh*NN + j)*NN + i] = pw;
    }
    denP[(size_t)jc*(NN*NH) + hh*NN + i] = denl;
}

// ---------------- Phase B: accP[jc] = P-chunk @ g_r ----------------
// lane = i (P coalesced b32); g_r 32-f segment via SMEM, A/B double-buffered
// (SMEM honors only lgkmcnt(0), so alternate full waits). 32 v_fma(s,v,v)/j.
// Epilogue: LDS transpose -> coalesced accP stores.
#define PVFMA(G0, G1, PP)                                           \
    { _Pragma("unroll") for (int q = 0; q < 4; ++q) {               \
        acc[q].x   += (PP)*G0[q*4+0]; acc[q].y   += (PP)*G0[q*4+1]; \
        acc[q].z   += (PP)*G0[q*4+2]; acc[q].w   += (PP)*G0[q*4+3]; \
        acc[4+q].x += (PP)*G1[q*4+0]; acc[4+q].y += (PP)*G1[q*4+1]; \
        acc[4+q].z += (PP)*G1[q*4+2]; acc[4+q].w += (PP)*G1[q*4+3]; } }

__global__ __launch_bounds__(256, 3) void gatv2_pv(
    const float* __restrict__ wsro, float* __restrict__ accP)
{
    __shared__ float sT[256*36];
    const float* g_r = wsro + OFF_GR;
    const float* P   = wsro + OFF_P;
    const int t  = threadIdx.x;
    const int jc = blockIdx.x;      // 16 j-chunks of 64
    const int ib = blockIdx.y;      // 4 i-blocks of 256
    const int fs = blockIdx.z;      // 8 f-segments of 32
    const int hh = fs >> 1;
    const int f0 = hh*64 + (fs & 1)*32;
    const int i  = ib*256 + t;

    float4 acc[8];
    #pragma unroll
    for (int q = 0; q < 8; ++q) acc[q] = make_float4(0.f,0.f,0.f,0.f);

    const int j0 = jc*64;
    const size_t pb0 = ((size_t)hh*NN)*NN + i;   // + j*NN per j

    fx16 a0, a1, b0, b1;
    {
        const float* gp = g_r + (size_t)j0*HF + f0;
        asm volatile(
            "s_load_dwordx16 %0, %2, 0x0\n\t"
            "s_load_dwordx16 %1, %2, 0x40\n\t"
            "s_waitcnt lgkmcnt(0)"
            : "=s"(a0), "=s"(a1) : "s"(gp));
    }
    float pA = P[pb0 + (size_t)j0*NN];

    for (int jj = 0; jj < 64; jj += 2) {
        const int j = j0 + jj;
        // issue B = row j+1 (no wait yet)
        {
            const float* gp = g_r + (size_t)(j+1)*HF + f0;
            asm volatile(
                "s_load_dwordx16 %0, %2, 0x0\n\t"
                "s_load_dwordx16 %1, %2, 0x40"
                : "=s"(b0), "=s"(b1) : "s"(gp));
        }
        const float pB = P[pb0 + (size_t)(j+1)*NN];
        PVFMA(a0, a1, pA)
        asm volatile("s_waitcnt lgkmcnt(0)");
        // issue A = row j+2 (clamped at chunk end; value unused then)
        {
            const int j2 = (jj + 2 < 64) ? (j + 2) : j0;
            const float* gp = g_r + (size_t)j2*HF + f0;
            asm volatile(
                "s_load_dwordx16 %0, %2, 0x0\n\t"
                "s_load_dwordx16 %1, %2, 0x40"
                : "=s"(a0), "=s"(a1) : "s"(gp));
            pA = P[pb0 + (size_t)j2*NN];
        }
        PVFMA(b0, b1, pB)
        asm volatile("s_waitcnt lgkmcnt(0)");
    }

    // transpose [256 i][32 f] via LDS -> coalesced accP stores
    #pragma unroll
    for (int q = 0; q < 8; ++q)
        *(float4*)&sT[t*36 + q*4] = acc[q];
    __syncthreads();
    #pragma unroll
    for (int rep = 0; rep < 8; ++rep) {
        const int idx = rep*256 + t;          // float4 index
        const int il = idx >> 3, fq = idx & 7;
        const float4 v = *(const float4*)&sT[il*36 + fq*4];
        *(float4*)&accP[(size_t)jc*(NN*HF) + (size_t)(ib*256 + il)*HF + f0 + fq*4] = v;
    }
}

// ---------------- Final: sum partials, /den, elu ----------------
__global__ __launch_bounds__(256) void gatv2_fin(
    const float* __restrict__ accP, const float* __restrict__ denP,
    const int* __restrict__ use_elu, float* __restrict__ out)
{
    const int idx4 = blockIdx.x*256 + threadIdx.x;  // float4 index over out
    const int i  = idx4 >> 6;
    const int hh = (idx4 >> 4) & 3;
    float4 s = make_float4(0.f,0.f,0.f,0.f);
    for (int c = 0; c < 16; ++c) {
        const float4 v = *(const float4*)&accP[(size_t)c*(NN*HF) + (size_t)idx4*4];
        s.x += v.x; s.y += v.y; s.z += v.z; s.w += v.w;
    }
    float d = 0.f;
    for (int c = 0; c < 32; ++c) d += denP[(size_t)c*(NN*NH) + hh*NN + i];
    const float rd = 1.f / d;
    float4 r = make_float4(s.x*rd, s.y*rd, s.z*rd, s.w*rd);
    if (*use_elu != 0) {
        r.x = (r.x > 0.f) ? r.x : expm1f(r.x);
        r.y = (r.y > 0.f) ? r.y : expm1f(r.y);
        r.z = (r.z > 0.f) ? r.z : expm1f(r.z);
        r.w = (r.w > 0.f) ? r.w : expm1f(r.w);
    }
    ((float4*)out)[idx4] = r;
}

extern "C" void kernel_launch(void* const* d_in, const int* in_sizes, int n_in,
                              void* d_out, int out_size, void* d_ws, size_t ws_size,
                              hipStream_t stream)
{
    const float* hmat = (const float*)d_in[0];
    const float* nei  = (const float*)d_in[1];
    const float* adj  = (const float*)d_in[2];
    const float* w_l  = (const float*)d_in[3];
    const float* w_r  = (const float*)d_in[4];
    const float* aw   = (const float*)d_in[5];
    const int*   uel  = (const int*)d_in[6];
    float* out = (float*)d_out;
    float* ws  = (float*)d_ws;

    hipLaunchKernelGGL(gatv2_gemm, dim3(64,4,2), dim3(256), 0, stream,
                       hmat, nei, w_l, w_r, aw, ws);
    hipLaunchKernelGGL(gatv2_e, dim3(32,4,4), dim3(256), 0, stream,
                       ws, adj, aw, ws + OFF_P, ws + OFF_DENP);
    hipLaunchKernelGGL(gatv2_pv, dim3(16,4,8), dim3(256), 0, stream,
                       ws, ws + OFF_ACCP);
    hipLaunchKernelGGL(gatv2_fin, dim3((NN*HF)/1024), dim3(256), 0, stream,
                       ws + OFF_ACCP, ws + OFF_DENP, uel, out);
}

// Round 6
// 139.990 us; speedup vs baseline: 1.2967x; 1.0417x over previous
//
#include <hip/hip_runtime.h>
#include <math.h>

#define NN 1024
#define KK 256
#define NH 4
#define FD 64
#define HF 256

typedef __attribute__((ext_vector_type(16))) float fx16;

// ---- workspace float offsets ----
#define OFF_GL   0
#define OFF_GR   (256*1024)
#define OFF_CL   (512*1024)
#define OFF_CR   (512*1024 + 4096)
#define OFF_DENP (512*1024 + 8192)          // 32 chunks x 4096
#define OFF_P    (768*1024)                 // 4M floats [h][j][i]
#define OFF_ACCP (OFF_P + 4*1024*1024)      // 32 chunks x 256K floats (32MB)

// ---------------- GEMM: G = A @ W, cl/cr fused, no atomics ----------------
__global__ __launch_bounds__(256) void gatv2_gemm(
    const float* __restrict__ hmat, const float* __restrict__ nei,
    const float* __restrict__ w_l, const float* __restrict__ w_r,
    const float* __restrict__ aw, float* __restrict__ ws)
{
    __shared__ float sA[16*260];
    const int t   = threadIdx.x;
    const int mb  = blockIdx.x;
    const int hd  = blockIdx.y;
    const int mat = blockIdx.z;
    const float* A = mat ? nei : hmat;
    const float* W = mat ? w_r : w_l;
    float* G  = ws + (mat ? OFF_GR : OFF_GL);
    float* CC = ws + (mat ? OFF_CR : OFF_CL);

    #pragma unroll
    for (int rep = 0; rep < 4; ++rep) {
        const int flat = rep*256 + t;
        const int r = flat >> 6, c = (flat & 63) << 2;
        *(float4*)&sA[r*260 + c] = *(const float4*)&A[(size_t)(mb*16 + r)*KK + c];
    }
    __syncthreads();

    const int m  = t >> 4;
    const int nq = t & 15;
    const int ng = hd*64 + (nq << 2);
    const float* Wp = W + ng;

    float4 acc = make_float4(0.f, 0.f, 0.f, 0.f);
    #pragma unroll 4
    for (int k0 = 0; k0 < KK; k0 += 4) {
        const float4 a4 = *(const float4*)&sA[m*260 + k0];
        const float4 w0 = *(const float4*)(Wp + (size_t)(k0+0)*HF);
        const float4 w1 = *(const float4*)(Wp + (size_t)(k0+1)*HF);
        const float4 w2 = *(const float4*)(Wp + (size_t)(k0+2)*HF);
        const float4 w3 = *(const float4*)(Wp + (size_t)(k0+3)*HF);
        acc.x += a4.x*w0.x; acc.y += a4.x*w0.y; acc.z += a4.x*w0.z; acc.w += a4.x*w0.w;
        acc.x += a4.y*w1.x; acc.y += a4.y*w1.y; acc.z += a4.y*w1.z; acc.w += a4.y*w1.w;
        acc.x += a4.z*w2.x; acc.y += a4.z*w2.y; acc.z += a4.z*w2.z; acc.w += a4.z*w2.w;
        acc.x += a4.w*w3.x; acc.y += a4.w*w3.y; acc.z += a4.w*w3.z; acc.w += a4.w*w3.w;
    }

    *(float4*)&G[(size_t)(mb*16 + m)*HF + ng] = acc;

    {
        const float4 w4 = ((const float4*)aw)[nq];
        float wd = w4.x*acc.x + w4.y*acc.y + w4.z*acc.z + w4.w*acc.w;
        wd += __shfl_xor(wd, 1);
        wd += __shfl_xor(wd, 2);
        wd += __shfl_xor(wd, 4);
        wd += __shfl_xor(wd, 8);
        if (nq == 0) CC[hd*NN + mb*16 + m] = 0.6f*wd;
    }
}

// ---------------- Phase A: e -> p = mask*exp(e), chunked den ----------------
#define EBLK(RV, QB)                                                \
    { _Pragma("unroll") for (int q = 0; q < 4; ++q) {               \
        const float4 wq = w[(QB)+q]; const float4 gq = gri[(QB)+q]; \
        e0 += wq.x * fabsf(RV[q*4+0] + gq.x);                       \
        e1 += wq.y * fabsf(RV[q*4+1] + gq.y);                       \
        e2 += wq.z * fabsf(RV[q*4+2] + gq.z);                       \
        e3 += wq.w * fabsf(RV[q*4+3] + gq.w); } }

__global__ __launch_bounds__(256, 3) void gatv2_e(
    const float* __restrict__ wsro, const float* __restrict__ adj,
    const float* __restrict__ aw, float* __restrict__ P,
    float* __restrict__ denP)
{
    __shared__ float s_w[64];
    const float* g_l = wsro + OFF_GL;
    const float* g_r = wsro + OFF_GR;
    const float* cl  = wsro + OFF_CL;
    const float* cr  = wsro + OFF_CR;
    const int t  = threadIdx.x;
    const int jc = blockIdx.x;   // 32 j-chunks of 32
    const int ib = blockIdx.y;   // 4
    const int hh = blockIdx.z;   // 4
    const int i  = ib*256 + t;

    if (t < 16) ((float4*)s_w)[t] = ((const float4*)aw)[t];
    __syncthreads();

    float4 w[16], gri[16];
    {
        const float4* gp = (const float4*)(g_r + (size_t)i*HF + hh*FD);
        #pragma unroll
        for (int q = 0; q < 16; ++q) {
            w[q]   = ((const float4*)s_w)[q];   // ds_read -> VGPR, per-lane
            gri[q] = gp[q];
        }
    }
    const float cri = cr[hh*NN + i];

    float denl = 0.f;
    const int j0 = jc*32;
    for (int jj = 0; jj < 32; ++jj) {
        const int j = j0 + jj;
        const float mask = adj[(size_t)j*NN + i];
        fx16 r0, r1, r2, r3; float clv;
        const float* rowp = g_l + (size_t)j*HF + hh*FD;
        const float* clp  = cl + hh*NN + j;
        asm volatile(
            "s_load_dwordx16 %0, %5, 0x0\n\t"
            "s_load_dwordx16 %1, %5, 0x40\n\t"
            "s_load_dwordx16 %2, %5, 0x80\n\t"
            "s_load_dwordx16 %3, %5, 0xc0\n\t"
            "s_load_dword %4, %6, 0x0\n\t"
            "s_waitcnt lgkmcnt(0)"
            : "=s"(r0), "=s"(r1), "=s"(r2), "=s"(r3), "=s"(clv)
            : "s"(rowp), "s"(clp));
        float e0 = 0.f, e1 = 0.f, e2 = 0.f, e3 = 0.f;
        EBLK(r0, 0) EBLK(r1, 4) EBLK(r2, 8) EBLK(r3, 12)
        const float e  = cri + clv + 0.4f*((e0+e1)+(e2+e3));
        const float pw = (mask != 0.f) ? __expf(e) : 0.f;
        denl += pw;
        P[((size_t)hh*NN + j)*NN + i] = pw;
    }
    denP[(size_t)jc*(NN*NH) + hh*NN + i] = denl;
}

// ---------------- Phase B: accP[jc] = P-chunk @ g_r ----------------
// jc=32 -> 1024 blocks = 4 blocks/CU = 4 waves/SIMD: SMEM wait stalls
// (~140cyc/pair) covered by 3 sibling waves -> VALU-bound (~4us model).
#define PVFMA(G0, G1, PP)                                           \
    { _Pragma("unroll") for (int q = 0; q < 4; ++q) {               \
        acc[q].x   += (PP)*G0[q*4+0]; acc[q].y   += (PP)*G0[q*4+1]; \
        acc[q].z   += (PP)*G0[q*4+2]; acc[q].w   += (PP)*G0[q*4+3]; \
        acc[4+q].x += (PP)*G1[q*4+0]; acc[4+q].y += (PP)*G1[q*4+1]; \
        acc[4+q].z += (PP)*G1[q*4+2]; acc[4+q].w += (PP)*G1[q*4+3]; } }

__global__ __launch_bounds__(256, 4) void gatv2_pv(
    const float* __restrict__ wsro, float* __restrict__ accP)
{
    __shared__ float sT[256*36];
    const float* g_r = wsro + OFF_GR;
    const float* P   = wsro + OFF_P;
    const int t  = threadIdx.x;
    const int jc = blockIdx.x;      // 32 j-chunks of 32
    const int ib = blockIdx.y;      // 4 i-blocks of 256
    const int fs = blockIdx.z;      // 8 f-segments of 32
    const int hh = fs >> 1;
    const int f0 = hh*64 + (fs & 1)*32;
    const int i  = ib*256 + t;

    float4 acc[8];
    #pragma unroll
    for (int q = 0; q < 8; ++q) acc[q] = make_float4(0.f,0.f,0.f,0.f);

    const int j0 = jc*32;
    const size_t pb0 = ((size_t)hh*NN)*NN + i;   // + j*NN per j

    fx16 a0, a1, b0, b1;
    {
        const float* gp = g_r + (size_t)j0*HF + f0;
        asm volatile(
            "s_load_dwordx16 %0, %2, 0x0\n\t"
            "s_load_dwordx16 %1, %2, 0x40\n\t"
            "s_waitcnt lgkmcnt(0)"
            : "=s"(a0), "=s"(a1) : "s"(gp));
    }
    float pA = P[pb0 + (size_t)j0*NN];

    for (int jj = 0; jj < 32; jj += 2) {
        const int j = j0 + jj;
        {
            const float* gp = g_r + (size_t)(j+1)*HF + f0;
            asm volatile(
                "s_load_dwordx16 %0, %2, 0x0\n\t"
                "s_load_dwordx16 %1, %2, 0x40"
                : "=s"(b0), "=s"(b1) : "s"(gp));
        }
        const float pB = P[pb0 + (size_t)(j+1)*NN];
        PVFMA(a0, a1, pA)
        asm volatile("s_waitcnt lgkmcnt(0)");
        {
            const int j2 = (jj + 2 < 32) ? (j + 2) : j0;
            const float* gp = g_r + (size_t)j2*HF + f0;
            asm volatile(
                "s_load_dwordx16 %0, %2, 0x0\n\t"
                "s_load_dwordx16 %1, %2, 0x40"
                : "=s"(a0), "=s"(a1) : "s"(gp));
            pA = P[pb0 + (size_t)j2*NN];
        }
        PVFMA(b0, b1, pB)
        asm volatile("s_waitcnt lgkmcnt(0)");
    }

    // transpose [256 i][32 f] via LDS -> coalesced accP stores
    #pragma unroll
    for (int q = 0; q < 8; ++q)
        *(float4*)&sT[t*36 + q*4] = acc[q];
    __syncthreads();
    #pragma unroll
    for (int rep = 0; rep < 8; ++rep) {
        const int idx = rep*256 + t;          // float4 index
        const int il = idx >> 3, fq = idx & 7;
        const float4 v = *(const float4*)&sT[il*36 + fq*4];
        *(float4*)&accP[(size_t)jc*(NN*HF) + (size_t)(ib*256 + il)*HF + f0 + fq*4] = v;
    }
}

// ---------------- Final: sum partials, /den, elu ----------------
__global__ __launch_bounds__(256) void gatv2_fin(
    const float* __restrict__ accP, const float* __restrict__ denP,
    const int* __restrict__ use_elu, float* __restrict__ out)
{
    const int idx4 = blockIdx.x*256 + threadIdx.x;  // float4 index over out
    const int i  = idx4 >> 6;
    const int hh = (idx4 >> 4) & 3;
    float4 s = make_float4(0.f,0.f,0.f,0.f);
    for (int c = 0; c < 32; ++c) {
        const float4 v = *(const float4*)&accP[(size_t)c*(NN*HF) + (size_t)idx4*4];
        s.x += v.x; s.y += v.y; s.z += v.z; s.w += v.w;
    }
    float d = 0.f;
    for (int c = 0; c < 32; ++c) d += denP[(size_t)c*(NN*NH) + hh*NN + i];
    const float rd = 1.f / d;
    float4 r = make_float4(s.x*rd, s.y*rd, s.z*rd, s.w*rd);
    if (*use_elu != 0) {
        r.x = (r.x > 0.f) ? r.x : expm1f(r.x);
        r.y = (r.y > 0.f) ? r.y : expm1f(r.y);
        r.z = (r.z > 0.f) ? r.z : expm1f(r.z);
        r.w = (r.w > 0.f) ? r.w : expm1f(r.w);
    }
    ((float4*)out)[idx4] = r;
}

extern "C" void kernel_launch(void* const* d_in, const int* in_sizes, int n_in,
                              void* d_out, int out_size, void* d_ws, size_t ws_size,
                              hipStream_t stream)
{
    const float* hmat = (const float*)d_in[0];
    const float* nei  = (const float*)d_in[1];
    const float* adj  = (const float*)d_in[2];
    const float* w_l  = (const float*)d_in[3];
    const float* w_r  = (const float*)d_in[4];
    const float* aw   = (const float*)d_in[5];
    const int*   uel  = (const int*)d_in[6];
    float* out = (float*)d_out;
    float* ws  = (float*)d_ws;

    hipLaunchKernelGGL(gatv2_gemm, dim3(64,4,2), dim3(256), 0, stream,
                       hmat, nei, w_l, w_r, aw, ws);
    hipLaunchKernelGGL(gatv2_e, dim3(32,4,4), dim3(256), 0, stream,
                       ws, adj, aw, ws + OFF_P, ws + OFF_DENP);
    hipLaunchKernelGGL(gatv2_pv, dim3(32,4,8), dim3(256), 0, stream,
                       ws, ws + OFF_ACCP);
    hipLaunchKernelGGL(gatv2_fin, dim3((NN*HF)/1024), dim3(256), 0, stream,
                       ws + OFF_ACCP, ws + OFF_DENP, uel, out);
}